// Round 15
// baseline (692.614 us; speedup 1.0000x reference)
//
#include <hip/hip_runtime.h>

// RVQTokenizer: x[16,2048,256] f32, codebooks[4,1024,256] f32.
// Outputs (flat f32): quant[16,2048,256], indices[4,16,2048] (as float),
// 4 scalar losses (all = total vq_loss).
#define B_    16
#define T_    2048
#define D_    256
#define Q_    4
#define K_    1024
#define NTOK  (B_ * T_)            // 32768
#define QUANT_N (NTOK * D_)        // 8388608
#define IDX_N   (Q_ * NTOK)        // 131072
#define LOSS_OFF (QUANT_N + IDX_N) // 8519680
#define MARGIN_V8   0.03f          // fp32-coarse window (fallback kernel)
#define RSTRIDE 260                // rs row stride (pad breaks bank conflicts)

// u32 score-key packing (verified PASS rounds 12-14):
// key = clamp(s*2048 + 2^21, [0, 2^22-1]) << 10 | n
#define KSCALE 2048.0f
#define KBIAS  2097152.0f          // 1<<21
#define KMAXF  4194303.0f          // (1<<22)-1
#define MKEY   220u                // hi-only fp16-A window (verified round 14)

typedef __attribute__((ext_vector_type(8))) _Float16 f16x8;
typedef __attribute__((ext_vector_type(4))) _Float16 f16x4;
typedef __attribute__((ext_vector_type(4))) float    f32x4;
typedef unsigned int u32;

__device__ __forceinline__ bool lt2(float v, int k, float w, int m) {
  return v < w || (v == w && k < m);
}
__device__ __forceinline__ u32 umn(u32 a, u32 b) { return a < b ? a : b; }
__device__ __forceinline__ u32 umx(u32 a, u32 b) { return a > b ? a : b; }

// insert key into sorted min-3 (t0<=t1<=t2): 5 min/max ops
__device__ __forceinline__ void kins3(u32& t0, u32& t1, u32& t2, u32 key) {
  u32 m0 = umx(t0, key); t0 = umn(t0, key);
  u32 m1 = umx(t1, m0);  t1 = umn(t1, m0);
  t2 = umn(t2, m1);
}

// counted-vmcnt wait + scheduler fence (rule #18)
#define WAITV(N)                                                    \
  do {                                                              \
    asm volatile("s_waitcnt vmcnt(" #N ")" ::: "memory");           \
    __builtin_amdgcn_sched_barrier(0);                              \
  } while (0)

// ---------------------------------------------------------------------------
// Bit-exact numpy emulation (verified PASS in rounds 8-14).
template <typename F>
__device__ __forceinline__ float np_sum256(F p) {
  float half[2];
#pragma unroll
  for (int h = 0; h < 2; ++h) {
    const int base = h * 128;
    float s[16];
#pragma unroll
    for (int l = 0; l < 16; ++l) {
      float t01 = __fadd_rn(p(base + l),      p(base + 16 + l));
      float t23 = __fadd_rn(p(base + 32 + l), p(base + 48 + l));
      float t45 = __fadd_rn(p(base + 64 + l), p(base + 80 + l));
      float t67 = __fadd_rn(p(base + 96 + l), p(base + 112 + l));
      s[l] = __fadd_rn(__fadd_rn(t01, t23), __fadd_rn(t45, t67));
    }
#pragma unroll
    for (int w = 8; w >= 1; w >>= 1)
#pragma unroll
      for (int l = 0; l < w; ++l) s[l] = __fadd_rn(s[l], s[l + w]);
    half[h] = s[0];
  }
  return __fadd_rn(half[0], half[1]);
}

template <typename F>
__device__ __forceinline__ float np_einsum256(F p) {
  float v[4] = {0.f, 0.f, 0.f, 0.f};
#pragma unroll
  for (int c = 0; c < 16; ++c) {
#pragma unroll
    for (int l = 0; l < 4; ++l) {
      int d0 = c * 16 + l;
      float t = __fadd_rn(p(d0 + 12), v[l]);
      t = __fadd_rn(p(d0 + 8), t);
      t = __fadd_rn(p(d0 + 4), t);
      v[l] = __fadd_rn(p(d0), t);
    }
  }
  return __fadd_rn(__fadd_rn(v[0], v[1]), __fadd_rn(v[2], v[3]));
}

__global__ void rvq_zero(float* __restrict__ ws) { ws[0] = 0.f; }

// ---------------------------------------------------------------------------
// Prep: cn[k]=||c_k||^2 (coarse only) and fp16 codebook copy.
__global__ __launch_bounds__(256) void rvq_prep(const float* __restrict__ cb,
                                                float* __restrict__ cn,
                                                _Float16* __restrict__ cbh) {
  int k = blockIdx.x * 4 + (threadIdx.x >> 6);   // 0..4095
  int l = threadIdx.x & 63;
  const float* row = cb + (size_t)k * D_;
  float s = 0.f;
#pragma unroll
  for (int j = 0; j < 4; ++j) { float v = row[l + 64 * j]; s += v * v; }
#pragma unroll
  for (int off = 32; off; off >>= 1) s += __shfl_xor(s, off);
  if (l == 0) cn[k] = s;
  int gid = blockIdx.x * 256 + threadIdx.x;      // 0..262143
  float4 v = *(const float4*)&cb[(size_t)gid * 4];
  f16x4 h;
  h[0] = (_Float16)v.x; h[1] = (_Float16)v.y;
  h[2] = (_Float16)v.z; h[3] = (_Float16)v.w;
  *(f16x4*)&cbh[(size_t)gid * 4] = h;
}

// ---------------------------------------------------------------------------
// Inline-asm B-group load: 8 x global_load_dwordx4 + 1 x cn load (9 events).
__device__ __forceinline__ void ldB_asm(const _Float16* cbhq, int g, int l15,
                                        int lg, f32x4* bb) {
  unsigned long long a =
      (unsigned long long)cbhq + ((unsigned long long)(g * 16 + l15) * 512 + lg * 16);
  asm volatile("global_load_dwordx4 %0, %1, off"             : "=v"(bb[0]) : "v"(a));
  asm volatile("global_load_dwordx4 %0, %1, off offset:64"   : "=v"(bb[1]) : "v"(a));
  asm volatile("global_load_dwordx4 %0, %1, off offset:128"  : "=v"(bb[2]) : "v"(a));
  asm volatile("global_load_dwordx4 %0, %1, off offset:192"  : "=v"(bb[3]) : "v"(a));
  asm volatile("global_load_dwordx4 %0, %1, off offset:256"  : "=v"(bb[4]) : "v"(a));
  asm volatile("global_load_dwordx4 %0, %1, off offset:320"  : "=v"(bb[5]) : "v"(a));
  asm volatile("global_load_dwordx4 %0, %1, off offset:384"  : "=v"(bb[6]) : "v"(a));
  asm volatile("global_load_dwordx4 %0, %1, off offset:448"  : "=v"(bb[7]) : "v"(a));
}
__device__ __forceinline__ void ldCN_asm(const float* cnq, int g, int l15,
                                         float& c) {
  unsigned long long a = (unsigned long long)(cnq + g * 16 + l15);
  asm volatile("global_load_dword %0, %1, off" : "=v"(c) : "v"(a));
}

#define BC8(v) __builtin_bit_cast(f16x8, v)

// score one codeword group: 2 independent MFMA chains of 4 (hi-only A).
#define SCORE_GRP(bb, grp, cval)                                              \
  do {                                                                        \
    const int n_ = (grp) * 16 + l15;                                          \
    f32x4 h0 = {0.f,0.f,0.f,0.f}, h1 = {0.f,0.f,0.f,0.f};                     \
    _Pragma("unroll")                                                         \
    for (int ks = 0; ks < 4; ++ks) {                                          \
      h0 = __builtin_amdgcn_mfma_f32_16x16x32_f16(Ah[ks],     BC8(bb[ks]),     h0, 0, 0, 0); \
      h1 = __builtin_amdgcn_mfma_f32_16x16x32_f16(Ah[ks + 4], BC8(bb[ks + 4]), h1, 0, 0, 0); \
    }                                                                         \
    float c2b_ = __builtin_fmaf((cval), KSCALE, KBIAS);                       \
    _Pragma("unroll")                                                         \
    for (int r = 0; r < 4; ++r) {                                             \
      float kf_ = __builtin_fmaf(h0[r] + h1[r], -2.f * KSCALE, c2b_);         \
      u32 kv_ = (u32)fminf(fmaxf(kf_, 0.f), KMAXF);                           \
      kins3(t0[r], t1[r], t2[r], (kv_ << 10) | (u32)n_);                      \
    }                                                                         \
  } while (0)

// ---------------------------------------------------------------------------
// MFMA RVQ v4: 16 tokens/block, 4 waves each scoring a DISJOINT quarter of
// the codebook (16 panels) for the same 16 tokens. LDS ~17.3 KB -> 4 blocks/
// CU (4 waves/SIMD, 2x TLP vs rounds 9-14). Cross-wave top-3 merge in LDS;
// np-bit-exact adjudication token-parallel on 16 lanes.
__global__ __launch_bounds__(256, 4) void rvq_mfma4(const float* __restrict__ x,
                                                    const float* __restrict__ cb,
                                                    const float* __restrict__ cn,
                                                    const _Float16* __restrict__ cbh,
                                                    float* __restrict__ out,
                                                    float* __restrict__ loss_ws) {
  __shared__ float rs[16 * RSTRIDE];   // 16.6 KB, rows padded to 260 floats
  __shared__ u32 wtop[4][16][3];       // per-wave top-3 keys per token
  __shared__ int bestk[16];

  const int tid  = threadIdx.x;
  const int tok0 = blockIdx.x * 16;
  const int lane = tid & 63;
  const int wv   = tid >> 6;       // wave id = codebook quarter
  const int l15  = lane & 15;      // A-row(token) / B-col / D-col
  const int lg   = lane >> 4;      // k-group / D-row-group
  const int ut   = tid >> 4, uc = tid & 15;   // streaming: 16 thr/token

  // ---- load x -> rs -------------------------------------------------------
#pragma unroll
  for (int j = 0; j < 4; ++j) {
    int c4 = j * 16 + uc;
    *(float4*)&rs[ut * RSTRIDE + c4 * 4] =
        *(const float4*)&x[(size_t)(tok0 + ut) * D_ + c4 * 4];
  }
  __syncthreads();

  float lsq = 0.f;

  for (int q = 0; q < Q_; ++q) {
    const float*    cbq  = cb  + (size_t)q * K_ * D_;
    const float*    cnq  = cn  + q * K_;
    const _Float16* cbhq = cbh + (size_t)q * K_ * D_;

    // ---- A fragments (fp16 hi only), same 16 tokens for every wave --------
    f16x8 Ah[8];
    {
      const float* rrow = &rs[l15 * RSTRIDE];
#pragma unroll
      for (int ks = 0; ks < 8; ++ks) {
        float4 v0 = *(const float4*)&rrow[ks * 32 + lg * 8];
        float4 v1 = *(const float4*)&rrow[ks * 32 + lg * 8 + 4];
        f16x8 h;
        h[0] = (_Float16)v0.x; h[1] = (_Float16)v0.y;
        h[2] = (_Float16)v0.z; h[3] = (_Float16)v0.w;
        h[4] = (_Float16)v1.x; h[5] = (_Float16)v1.y;
        h[6] = (_Float16)v1.z; h[7] = (_Float16)v1.w;
        Ah[ks] = h;
      }
    }

    // ---- top-3 u32 keys for tokens lg*4 + r --------------------------------
    u32 t0[4], t1[4], t2[4];
#pragma unroll
    for (int r = 0; r < 4; ++r) { t0[r] = t1[r] = t2[r] = 0xFFFFFFFFu; }

    // ---- scoring: 16 panels (this wave's quarter), 2-buffer asm pipeline --
    {
      const int base = wv * 16;
      f32x4 b0[8], b1[8];
      float cA, cB;
      ldB_asm(cbhq, base, l15, lg, b0); ldCN_asm(cnq, base, l15, cA);
      for (int p = 0; p < 7; ++p) {     // local groups 2p, 2p+1 (0..13)
        const int i = 2 * p;
        ldB_asm(cbhq, base + i + 1, l15, lg, b1); ldCN_asm(cnq, base + i + 1, l15, cB);
        WAITV(9);                       // retire b0
        SCORE_GRP(b0, base + i, cA);
        ldB_asm(cbhq, base + i + 2, l15, lg, b0); ldCN_asm(cnq, base + i + 2, l15, cA);
        WAITV(9);                       // retire b1
        SCORE_GRP(b1, base + i + 1, cB);
      }
      ldB_asm(cbhq, base + 15, l15, lg, b1); ldCN_asm(cnq, base + 15, l15, cB);
      WAITV(9);                         // retire b0 (group 14)
      SCORE_GRP(b0, base + 14, cA);
      WAITV(0);                         // retire b1 (group 15)
      SCORE_GRP(b1, base + 15, cB);
    }

    // ---- merge top-3 across the 16 l15 lanes (intra-wave) ------------------
#pragma unroll
    for (int r = 0; r < 4; ++r) {
#pragma unroll
      for (int off = 1; off < 16; off <<= 1) {
        u32 o0 = (u32)__shfl_xor((int)t0[r], off);
        u32 o1 = (u32)__shfl_xor((int)t1[r], off);
        u32 o2 = (u32)__shfl_xor((int)t2[r], off);
        kins3(t0[r], t1[r], t2[r], o0);
        kins3(t0[r], t1[r], t2[r], o1);
        kins3(t0[r], t1[r], t2[r], o2);
      }
    }
    if (l15 == 0) {
#pragma unroll
      for (int r = 0; r < 4; ++r) {
        int t = lg * 4 + r;
        wtop[wv][t][0] = t0[r]; wtop[wv][t][1] = t1[r]; wtop[wv][t][2] = t2[r];
      }
    }
    __syncthreads();

    // ---- final cross-wave merge + np-exact adjudication (16 lanes) --------
    if (tid < 16) {
      const int t = tid;
      u32 a0 = wtop[0][t][0], a1 = wtop[0][t][1], a2 = wtop[0][t][2];
#pragma unroll
      for (int w = 1; w < 4; ++w) {
        kins3(a0, a1, a2, wtop[w][t][0]);
        kins3(a0, a1, a2, wtop[w][t][1]);
        kins3(a0, a1, a2, wtop[w][t][2]);
      }
      int kk = (int)(a0 & 1023u);
      u32 s0 = a0 >> 10, s1 = a1 >> 10, s2 = a2 >> 10;
      if (s1 - s0 < MKEY) {
        const float* rsrow = &rs[t * RSTRIDE];
        float A = np_sum256([&](int d) {
          float rr = rsrow[d]; return __fmul_rn(rr, rr);
        });
        int cand[3]; int nc2 = 1;
        cand[0] = kk;
        cand[nc2++] = (int)(a1 & 1023u);
        if (s2 - s0 < MKEY) cand[nc2++] = (int)(a2 & 1023u);
        float bd = 3.4e38f; int bk2 = 0x7FFFFFFF;
        for (int i = 0; i < nc2; ++i) {
          const float* crow = cbq + (size_t)cand[i] * D_;
          float E = np_einsum256([&](int d) {
            return __fmul_rn(rsrow[d], crow[d]);
          });
          float C = np_sum256([&](int d) {
            float cc = crow[d]; return __fmul_rn(cc, cc);
          });
          float dd = __fadd_rn(__fsub_rn(A, __fmul_rn(2.f, E)), C);
          if (dd < bd || (dd == bd && cand[i] < bk2)) { bd = dd; bk2 = cand[i]; }
        }
        kk = bk2;
      }
      bestk[t] = kk;
      out[QUANT_N + q * NTOK + tok0 + t] = (float)kk;
    }
    __syncthreads();          // bestk visible

    // ---- residual update + loss -------------------------------------------
    {
      int kk = bestk[ut] & (K_ - 1);
      const float* crow = cbq + (size_t)kk * D_;
#pragma unroll
      for (int j = 0; j < 4; ++j) {
        int c4 = j * 16 + uc;
        float4 cv = *(const float4*)&crow[c4 * 4];
        float4 rv = *(float4*)&rs[ut * RSTRIDE + c4 * 4];
        rv.x -= cv.x; rv.y -= cv.y; rv.z -= cv.z; rv.w -= cv.w;
        *(float4*)&rs[ut * RSTRIDE + c4 * 4] = rv;
        lsq += rv.x * rv.x + rv.y * rv.y + rv.z * rv.z + rv.w * rv.w;
      }
    }
    __syncthreads();          // rs updated before next stage's A-read
  }

  // ---- quant = x - r_final -------------------------------------------------
#pragma unroll
  for (int j = 0; j < 4; ++j) {
    int c4 = j * 16 + uc;
    float4 xv = *(const float4*)&x[(size_t)(tok0 + ut) * D_ + c4 * 4];
    float4 rv = *(const float4*)&rs[ut * RSTRIDE + c4 * 4];
    float4 o;
    o.x = xv.x - rv.x; o.y = xv.y - rv.y;
    o.z = xv.z - rv.z; o.w = xv.w - rv.w;
    *(float4*)&out[(size_t)(tok0 + ut) * D_ + c4 * 4] = o;
  }

  // ---- loss: wave reduce + one atomic per wave -----------------------------
#pragma unroll
  for (int off = 32; off; off >>= 1) lsq += __shfl_xor(lsq, off);
  if ((tid & 63) == 0) atomicAdd(loss_ws, lsq);
}

// ---------------------------------------------------------------------------
// FALLBACK (round-8 kernel, verbatim): used only if ws is too small for cbh.
__global__ __launch_bounds__(256) void rvq_cnorm(const float* __restrict__ cb,
                                                 float* __restrict__ cn) {
  int k = blockIdx.x * 4 + (threadIdx.x >> 6);
  int l = threadIdx.x & 63;
  const float* row = cb + (size_t)k * D_;
  float s = 0.f;
#pragma unroll
  for (int j = 0; j < 4; ++j) { float v = row[l + 64 * j]; s += v * v; }
#pragma unroll
  for (int off = 32; off; off >>= 1) s += __shfl_xor(s, off);
  if (l == 0) cn[k] = s;
}

__global__ __launch_bounds__(256, 2) void rvq_main_v8(const float* __restrict__ x,
                                                      const float* __restrict__ cb,
                                                      const float* __restrict__ cn,
                                                      float* __restrict__ out,
                                                      float* __restrict__ loss_ws) {
  __shared__ float4 rs4[32 * 64];
  __shared__ float4 cbt[64 * 16];
  __shared__ int bestk[32];
  const int tid  = threadIdx.x;
  const int tok0 = blockIdx.x * 32;
  const int ut = tid >> 3, uc = tid & 7;
  const int ty = tid >> 4, tx = tid & 15;
  const int t0 = ty * 2;
#pragma unroll
  for (int j = 0; j < 8; ++j) {
    int c4 = uc * 8 + j;
    float4 v = *(const float4*)&x[(size_t)(tok0 + ut) * D_ + c4 * 4];
    rs4[ut * 64 + (c4 ^ ((ut >> 2) & 3))] = v;
  }
  __syncthreads();
  float lsq = 0.f;
  for (int q = 0; q < Q_; ++q) {
    const float* cbq = cb + (size_t)q * K_ * D_;
    const float* cnq = cn + q * K_;
    float v1[2], v2[2]; int k1[2], k2[2];
#pragma unroll
    for (int i = 0; i < 2; ++i) { v1[i] = v2[i] = 3.4e38f; k1[i] = k2[i] = 0x7FFFFFFF; }
    for (int nc = 0; nc < 16; ++nc) {
      float acc[2][4];
#pragma unroll
      for (int i = 0; i < 2; ++i)
#pragma unroll
        for (int j = 0; j < 4; ++j) acc[i][j] = 0.f;
      for (int dc = 0; dc < 4; ++dc) {
        __syncthreads();
#pragma unroll
        for (int i = 0; i < 4; ++i) {
          int f = i * 256 + tid;
          int row = f >> 4, c = f & 15;
          float4 v = *(const float4*)&cbq[(size_t)(nc * 64 + row) * D_ + dc * 64 + c * 4];
          cbt[row * 16 + (c ^ (row >> 2))] = v;
        }
        __syncthreads();
#pragma unroll
        for (int d4 = 0; d4 < 16; ++d4) {
          float4 a[2], b[4];
#pragma unroll
          for (int i = 0; i < 2; ++i) {
            int t = t0 + i;
            int c4 = dc * 16 + d4;
            a[i] = rs4[t * 64 + (c4 ^ ((t >> 2) & 3))];
          }
#pragma unroll
          for (int j = 0; j < 4; ++j) {
            int row = tx * 4 + j;
            b[j] = cbt[row * 16 + (d4 ^ tx)];
          }
#pragma unroll
          for (int i = 0; i < 2; ++i)
#pragma unroll
            for (int j = 0; j < 4; ++j)
              acc[i][j] += a[i].x * b[j].x + a[i].y * b[j].y +
                           a[i].z * b[j].z + a[i].w * b[j].w;
        }
      }
#pragma unroll
      for (int j = 0; j < 4; ++j) {
        int k = nc * 64 + tx * 4 + j;
        float c2 = cnq[k];
#pragma unroll
        for (int i = 0; i < 2; ++i) {
          float s = c2 - 2.f * acc[i][j];
          if (lt2(s, k, v1[i], k1[i])) { v2[i] = v1[i]; k2[i] = k1[i]; v1[i] = s; k1[i] = k; }
          else if (lt2(s, k, v2[i], k2[i])) { v2[i] = s; k2[i] = k; }
        }
      }
    }
#pragma unroll
    for (int i = 0; i < 2; ++i) {
      float a1 = v1[i]; int b1 = k1[i];
      float a2 = v2[i]; int b2 = k2[i];
#pragma unroll
      for (int off = 1; off < 16; off <<= 1) {
        float o1 = __shfl_xor(a1, off); int p1 = __shfl_xor(b1, off);
        float o2 = __shfl_xor(a2, off); int p2 = __shfl_xor(b2, off);
        if (lt2(o1, p1, a1, b1)) {
          if (lt2(a1, b1, o2, p2)) { a2 = a1; b2 = b1; } else { a2 = o2; b2 = p2; }
          a1 = o1; b1 = p1;
        } else if (lt2(o1, p1, a2, b2)) { a2 = o1; b2 = p1; }
      }
      if (tx == 0) {
        int t = t0 + i;
        int kk = b1 & (K_ - 1);
        if (a2 - a1 < MARGIN_V8) {
          int kb = b2 & (K_ - 1);
          const float* rowA = cbq + (size_t)kk * D_;
          const float* rowB = cbq + (size_t)kb * D_;
          const float* rsf = (const float*)rs4;
          const int tt = t;
          auto rd = [&](int d) -> float {
            return rsf[(tt * 64 + ((d >> 2) ^ ((tt >> 2) & 3))) * 4 + (d & 3)];
          };
          float A  = np_sum256([&](int d) { float r = rd(d); return __fmul_rn(r, r); });
          float Ea = np_einsum256([&](int d) { return __fmul_rn(rd(d), rowA[d]); });
          float Ca = np_sum256([&](int d) { float c = rowA[d]; return __fmul_rn(c, c); });
          float Eb = np_einsum256([&](int d) { return __fmul_rn(rd(d), rowB[d]); });
          float Cb = np_sum256([&](int d) { float c = rowB[d]; return __fmul_rn(c, c); });
          float da = __fadd_rn(__fsub_rn(A, __fmul_rn(2.f, Ea)), Ca);
          float db = __fadd_rn(__fsub_rn(A, __fmul_rn(2.f, Eb)), Cb);
          if (db < da || (db == da && kb < kk)) kk = kb;
        }
        bestk[t] = kk;
        out[QUANT_N + q * NTOK + tok0 + t] = (float)kk;
      }
    }
    __syncthreads();
    {
      int kk = bestk[ut] & (K_ - 1);
      const float* crow = cbq + (size_t)kk * D_;
#pragma unroll
      for (int j = 0; j < 8; ++j) {
        int c4 = uc * 8 + j;
        float4 cv = *(const float4*)&crow[c4 * 4];
        int slot = ut * 64 + (c4 ^ ((ut >> 2) & 3));
        float4 rv = rs4[slot];
        rv.x -= cv.x; rv.y -= cv.y; rv.z -= cv.z; rv.w -= cv.w;
        rs4[slot] = rv;
        lsq += rv.x * rv.x + rv.y * rv.y + rv.z * rv.z + rv.w * rv.w;
      }
    }
  }
  __syncthreads();
#pragma unroll
  for (int j = 0; j < 8; ++j) {
    int c4 = uc * 8 + j;
    float4 xv = *(const float4*)&x[(size_t)(tok0 + ut) * D_ + c4 * 4];
    float4 rv = rs4[ut * 64 + (c4 ^ ((ut >> 2) & 3))];
    float4 o;
    o.x = xv.x - rv.x; o.y = xv.y - rv.y;
    o.z = xv.z - rv.z; o.w = xv.w - rv.w;
    *(float4*)&out[(size_t)(tok0 + ut) * D_ + c4 * 4] = o;
  }
#pragma unroll
  for (int off = 32; off; off >>= 1) lsq += __shfl_xor(lsq, off);
  if ((tid & 63) == 0) atomicAdd(loss_ws, lsq);
}

// ---------------------------------------------------------------------------
__global__ void rvq_finalize(const float* __restrict__ ws,
                             float* __restrict__ out) {
  if (threadIdx.x == 0) {
    float loss = 1.25f * ws[0] * (1.0f / (float)QUANT_N);
#pragma unroll
    for (int i = 0; i < 4; ++i) out[LOSS_OFF + i] = loss;
  }
}

// ---------------------------------------------------------------------------
extern "C" void kernel_launch(void* const* d_in, const int* in_sizes, int n_in,
                              void* d_out, int out_size, void* d_ws, size_t ws_size,
                              hipStream_t stream) {
  const float* x  = (const float*)d_in[0];
  const float* cb = (const float*)d_in[1];
  if (n_in >= 2 && in_sizes[0] != QUANT_N) {
    x  = (const float*)d_in[1];
    cb = (const float*)d_in[0];
  }
  float* out = (float*)d_out;

  float* ws = (float*)d_ws;
  float* cn = ws + 64;                                  // 4096 f32
  _Float16* cbh = (_Float16*)(ws + 64 + Q_ * K_);       // 2 MB fp16 codebook
  size_t need = (size_t)(64 + Q_ * K_) * 4 + (size_t)Q_ * K_ * D_ * 2 + 256;

  rvq_zero<<<1, 1, 0, stream>>>(ws);
  if (ws_size >= need) {
    rvq_prep<<<Q_ * K_ / 4, 256, 0, stream>>>(cb, cn, cbh);
    rvq_mfma4<<<NTOK / 16, 256, 0, stream>>>(x, cb, cn, cbh, out, ws);
  } else {
    rvq_cnorm<<<Q_ * K_ / 4, 256, 0, stream>>>(cb, cn);
    rvq_main_v8<<<NTOK / 32, 256, 0, stream>>>(x, cb, cn, out, ws);
  }
  rvq_finalize<<<1, 64, 0, stream>>>(ws, out);
}

// Round 16
// 504.471 us; speedup vs baseline: 1.3729x; 1.3729x over previous
//
#include <hip/hip_runtime.h>

// RVQTokenizer: x[16,2048,256] f32, codebooks[4,1024,256] f32.
// Outputs (flat f32): quant[16,2048,256], indices[4,16,2048] (as float),
// 4 scalar losses (all = total vq_loss).
#define B_    16
#define T_    2048
#define D_    256
#define Q_    4
#define K_    1024
#define NTOK  (B_ * T_)            // 32768
#define QUANT_N (NTOK * D_)        // 8388608
#define IDX_N   (Q_ * NTOK)        // 131072
#define LOSS_OFF (QUANT_N + IDX_N) // 8519680
#define MARGIN_V8   0.03f          // fp32-coarse window (fallback kernel)
#define RSTRIDE 260                // rs row stride (2-way banks, 16B aligned)
#define TPB5  128                  // tokens per block (main kernel)

// u32 score-key packing (verified PASS rounds 12-15):
// key = clamp(s*2048 + 2^21, [0, 2^22-1]) << 10 | n
#define KSCALE 2048.0f
#define KBIAS  2097152.0f          // 1<<21
#define KMAXF  4194303.0f          // (1<<22)-1
#define MKEY   220u                // hi-only fp16-A window (verified r14/r15)

typedef __attribute__((ext_vector_type(8))) _Float16 f16x8;
typedef __attribute__((ext_vector_type(4))) _Float16 f16x4;
typedef __attribute__((ext_vector_type(4))) float    f32x4;
typedef unsigned int u32;

__device__ __forceinline__ bool lt2(float v, int k, float w, int m) {
  return v < w || (v == w && k < m);
}
__device__ __forceinline__ u32 umn(u32 a, u32 b) { return a < b ? a : b; }
__device__ __forceinline__ u32 umx(u32 a, u32 b) { return a > b ? a : b; }

// insert key into sorted min-3 (t0<=t1<=t2): 5 min/max ops
__device__ __forceinline__ void kins3(u32& t0, u32& t1, u32& t2, u32 key) {
  u32 m0 = umx(t0, key); t0 = umn(t0, key);
  u32 m1 = umx(t1, m0);  t1 = umn(t1, m0);
  t2 = umn(t2, m1);
}

// ---------------------------------------------------------------------------
// Bit-exact numpy emulation (verified PASS in rounds 8-15).
template <typename F>
__device__ __forceinline__ float np_sum256(F p) {
  float half[2];
#pragma unroll
  for (int h = 0; h < 2; ++h) {
    const int base = h * 128;
    float s[16];
#pragma unroll
    for (int l = 0; l < 16; ++l) {
      float t01 = __fadd_rn(p(base + l),      p(base + 16 + l));
      float t23 = __fadd_rn(p(base + 32 + l), p(base + 48 + l));
      float t45 = __fadd_rn(p(base + 64 + l), p(base + 80 + l));
      float t67 = __fadd_rn(p(base + 96 + l), p(base + 112 + l));
      s[l] = __fadd_rn(__fadd_rn(t01, t23), __fadd_rn(t45, t67));
    }
#pragma unroll
    for (int w = 8; w >= 1; w >>= 1)
#pragma unroll
      for (int l = 0; l < w; ++l) s[l] = __fadd_rn(s[l], s[l + w]);
    half[h] = s[0];
  }
  return __fadd_rn(half[0], half[1]);
}

template <typename F>
__device__ __forceinline__ float np_einsum256(F p) {
  float v[4] = {0.f, 0.f, 0.f, 0.f};
#pragma unroll
  for (int c = 0; c < 16; ++c) {
#pragma unroll
    for (int l = 0; l < 4; ++l) {
      int d0 = c * 16 + l;
      float t = __fadd_rn(p(d0 + 12), v[l]);
      t = __fadd_rn(p(d0 + 8), t);
      t = __fadd_rn(p(d0 + 4), t);
      v[l] = __fadd_rn(p(d0), t);
    }
  }
  return __fadd_rn(__fadd_rn(v[0], v[1]), __fadd_rn(v[2], v[3]));
}

__global__ void rvq_zero(float* __restrict__ ws) { ws[0] = 0.f; }

// ---------------------------------------------------------------------------
// Prep: cn[k]=||c_k||^2 (coarse only) and fp16 codebook copy.
__global__ __launch_bounds__(256) void rvq_prep(const float* __restrict__ cb,
                                                float* __restrict__ cn,
                                                _Float16* __restrict__ cbh) {
  int k = blockIdx.x * 4 + (threadIdx.x >> 6);   // 0..4095
  int l = threadIdx.x & 63;
  const float* row = cb + (size_t)k * D_;
  float s = 0.f;
#pragma unroll
  for (int j = 0; j < 4; ++j) { float v = row[l + 64 * j]; s += v * v; }
#pragma unroll
  for (int off = 32; off; off >>= 1) s += __shfl_xor(s, off);
  if (l == 0) cn[k] = s;
  int gid = blockIdx.x * 256 + threadIdx.x;      // 0..262143
  float4 v = *(const float4*)&cb[(size_t)gid * 4];
  f16x4 h;
  h[0] = (_Float16)v.x; h[1] = (_Float16)v.y;
  h[2] = (_Float16)v.z; h[3] = (_Float16)v.w;
  *(f16x4*)&cbh[(size_t)gid * 4] = h;
}

// ---------------------------------------------------------------------------
// Stage one 16cw x 256d fp16 panel (8 KB) into LDS via global_load_lds.
// 512 threads x 16B. LDS dest is linear (wave-uniform base + lane*16);
// the XOR swizzle is applied on the GLOBAL source (T2/m173 pattern):
// LDS[cw][s] = G[cw][s ^ (cw&7)]   (s = 16B-chunk index 0..31)
__device__ __forceinline__ void stage_panel(const _Float16* __restrict__ cbhq,
                                            int g, int tid, int wv,
                                            _Float16* panel) {
  int cw = tid >> 5, s = tid & 31;
  const _Float16* src =
      cbhq + (size_t)g * (16 * D_) + cw * D_ + ((s ^ (cw & 7)) * 8);
  __builtin_amdgcn_global_load_lds(
      (const __attribute__((address_space(1))) void*)src,
      (__attribute__((address_space(3))) void*)(panel + (size_t)wv * 512),
      16, 0, 0);
}

// ---------------------------------------------------------------------------
// MFMA RVQ v5: 128 tokens/block, 512 threads (8 waves x 16-token M-tiles,
// each wave scores ALL codewords for its tokens). B panel staged ONCE per
// block into LDS (double-buffered) -> per-CU L2 traffic 64MB -> 8MB.
// rs fp32 in LDS (padded stride). One barrier per group (m97 overlap).
__global__ __launch_bounds__(512, 2) void rvq_mfma5(const float* __restrict__ x,
                                                    const float* __restrict__ cb,
                                                    const float* __restrict__ cn,
                                                    const _Float16* __restrict__ cbh,
                                                    float* __restrict__ out,
                                                    float* __restrict__ loss_ws) {
  __shared__ float rs[TPB5 * RSTRIDE];      // 133 KB
  __shared__ _Float16 bpan[2][16 * 256];    // 2 x 8 KB panels
  __shared__ int bestk[TPB5];

  const int tid  = threadIdx.x;
  const int tok0 = blockIdx.x * TPB5;
  const int lane = tid & 63;
  const int wv   = tid >> 6;       // wave id = token M-tile (wv*16..+15)
  const int l15  = lane & 15;      // A-row(token) / B-col(cw) / D-col
  const int lg   = lane >> 4;      // k-group / D-row-group
  const int ut   = tid >> 2, uc = tid & 3;   // streaming: 4 thr/token

  // ---- load x -> rs -------------------------------------------------------
#pragma unroll
  for (int j = 0; j < 16; ++j) {
    int c4 = j * 4 + uc;
    *(float4*)&rs[ut * RSTRIDE + c4 * 4] =
        *(const float4*)&x[(size_t)(tok0 + ut) * D_ + c4 * 4];
  }
  __syncthreads();

  float lsq = 0.f;

  for (int q = 0; q < Q_; ++q) {
    const float*    cbq  = cb  + (size_t)q * K_ * D_;
    const float*    cnq  = cn  + q * K_;
    const _Float16* cbhq = cbh + (size_t)q * K_ * D_;

    // ---- A fragments (fp16 hi only) for this wave's 16 token rows ---------
    f16x8 Ah[8];
    {
      const float* rrow = &rs[(wv * 16 + l15) * RSTRIDE];
#pragma unroll
      for (int ks = 0; ks < 8; ++ks) {
        float4 v0 = *(const float4*)&rrow[ks * 32 + lg * 8];
        float4 v1 = *(const float4*)&rrow[ks * 32 + lg * 8 + 4];
        f16x8 h;
        h[0] = (_Float16)v0.x; h[1] = (_Float16)v0.y;
        h[2] = (_Float16)v0.z; h[3] = (_Float16)v0.w;
        h[4] = (_Float16)v1.x; h[5] = (_Float16)v1.y;
        h[6] = (_Float16)v1.z; h[7] = (_Float16)v1.w;
        Ah[ks] = h;
      }
    }

    // ---- top-3 u32 keys: tokens m = wv*16 + lg*4 + r ----------------------
    u32 t0[4], t1[4], t2[4];
#pragma unroll
    for (int r = 0; r < 4; ++r) { t0[r] = t1[r] = t2[r] = 0xFFFFFFFFu; }

    // ---- scoring: 64 groups, panel double-buffered in LDS -----------------
    stage_panel(cbhq, 0, tid, wv, bpan[0]);
    __syncthreads();                       // panel 0 resident

    for (int g = 0; g < 64; ++g) {
      if (g + 1 < 64) stage_panel(cbhq, g + 1, tid, wv, bpan[(g + 1) & 1]);

      const _Float16* P = bpan[g & 1];
      f16x8 b[8];
#pragma unroll
      for (int ks = 0; ks < 8; ++ks)
        b[ks] = *(const f16x8*)&P[l15 * 256 + (((ks * 4 + lg) ^ (l15 & 7)) * 8)];

      f32x4 h0 = {0.f, 0.f, 0.f, 0.f}, h1 = {0.f, 0.f, 0.f, 0.f};
#pragma unroll
      for (int ks = 0; ks < 4; ++ks) {
        h0 = __builtin_amdgcn_mfma_f32_16x16x32_f16(Ah[ks],     b[ks],     h0, 0, 0, 0);
        h1 = __builtin_amdgcn_mfma_f32_16x16x32_f16(Ah[ks + 4], b[ks + 4], h1, 0, 0, 0);
      }
      const int n = g * 16 + l15;
      float c2b = __builtin_fmaf(cnq[n], KSCALE, KBIAS);
#pragma unroll
      for (int r = 0; r < 4; ++r) {
        float kf = __builtin_fmaf(h0[r] + h1[r], -2.f * KSCALE, c2b);
        u32 kv = (u32)fminf(fmaxf(kf, 0.f), KMAXF);
        kins3(t0[r], t1[r], t2[r], (kv << 10) | (u32)n);
      }
      __syncthreads();   // drains stage(g+1) [vmcnt(0) before s_barrier];
                         // orders buffer reuse across waves
    }

    // ---- merge top-3 across the 16 l15 lanes (intra-wave) ------------------
#pragma unroll
    for (int r = 0; r < 4; ++r) {
#pragma unroll
      for (int off = 1; off < 16; off <<= 1) {
        u32 o0 = (u32)__shfl_xor((int)t0[r], off);
        u32 o1 = (u32)__shfl_xor((int)t1[r], off);
        u32 o2 = (u32)__shfl_xor((int)t2[r], off);
        kins3(t0[r], t1[r], t2[r], o0);
        kins3(t0[r], t1[r], t2[r], o1);
        kins3(t0[r], t1[r], t2[r], o2);
      }
    }

    // ---- leaders adjudicate (np-bit-exact) + write indices ----------------
    if (l15 == 0) {
#pragma unroll
      for (int r = 0; r < 4; ++r) {
        int t = wv * 16 + lg * 4 + r;     // local token
        int kk = (int)(t0[r] & 1023u);
        u32 s0 = t0[r] >> 10, s1 = t1[r] >> 10, s2 = t2[r] >> 10;
        if (s1 - s0 < MKEY) {
          const float* rsrow = &rs[t * RSTRIDE];
          float A = np_sum256([&](int d) {
            float rr = rsrow[d]; return __fmul_rn(rr, rr);
          });
          int cand[3]; int nc2 = 1;
          cand[0] = kk;
          cand[nc2++] = (int)(t1[r] & 1023u);
          if (s2 - s0 < MKEY) cand[nc2++] = (int)(t2[r] & 1023u);
          float bd = 3.4e38f; int bk2 = 0x7FFFFFFF;
          for (int i = 0; i < nc2; ++i) {
            const float* crow = cbq + (size_t)cand[i] * D_;
            float E = np_einsum256([&](int d) {
              return __fmul_rn(rsrow[d], crow[d]);
            });
            float C = np_sum256([&](int d) {
              float cc = crow[d]; return __fmul_rn(cc, cc);
            });
            float dd = __fadd_rn(__fsub_rn(A, __fmul_rn(2.f, E)), C);
            if (dd < bd || (dd == bd && cand[i] < bk2)) { bd = dd; bk2 = cand[i]; }
          }
          kk = bk2;
        }
        bestk[t] = kk;
        out[QUANT_N + q * NTOK + tok0 + t] = (float)kk;
      }
    }
    __syncthreads();          // bestk visible; rs reads (A/adjudicate) done

    // ---- residual update + loss -------------------------------------------
    {
      int kk = bestk[ut] & (K_ - 1);
      const float* crow = cbq + (size_t)kk * D_;
#pragma unroll
      for (int j = 0; j < 16; ++j) {
        int c4 = j * 4 + uc;
        float4 cv = *(const float4*)&crow[c4 * 4];
        float4 rv = *(float4*)&rs[ut * RSTRIDE + c4 * 4];
        rv.x -= cv.x; rv.y -= cv.y; rv.z -= cv.z; rv.w -= cv.w;
        *(float4*)&rs[ut * RSTRIDE + c4 * 4] = rv;
        lsq += rv.x * rv.x + rv.y * rv.y + rv.z * rv.z + rv.w * rv.w;
      }
    }
    __syncthreads();          // rs updated before next stage's A-read
  }

  // ---- quant = x - r_final -------------------------------------------------
#pragma unroll
  for (int j = 0; j < 16; ++j) {
    int c4 = j * 4 + uc;
    float4 xv = *(const float4*)&x[(size_t)(tok0 + ut) * D_ + c4 * 4];
    float4 rv = *(const float4*)&rs[ut * RSTRIDE + c4 * 4];
    float4 o;
    o.x = xv.x - rv.x; o.y = xv.y - rv.y;
    o.z = xv.z - rv.z; o.w = xv.w - rv.w;
    *(float4*)&out[(size_t)(tok0 + ut) * D_ + c4 * 4] = o;
  }

  // ---- loss: wave reduce + one atomic per wave -----------------------------
#pragma unroll
  for (int off = 32; off; off >>= 1) lsq += __shfl_xor(lsq, off);
  if ((tid & 63) == 0) atomicAdd(loss_ws, lsq);
}

// ---------------------------------------------------------------------------
// FALLBACK (round-8 kernel, verbatim): used only if ws is too small for cbh.
__global__ __launch_bounds__(256) void rvq_cnorm(const float* __restrict__ cb,
                                                 float* __restrict__ cn) {
  int k = blockIdx.x * 4 + (threadIdx.x >> 6);
  int l = threadIdx.x & 63;
  const float* row = cb + (size_t)k * D_;
  float s = 0.f;
#pragma unroll
  for (int j = 0; j < 4; ++j) { float v = row[l + 64 * j]; s += v * v; }
#pragma unroll
  for (int off = 32; off; off >>= 1) s += __shfl_xor(s, off);
  if (l == 0) cn[k] = s;
}

__global__ __launch_bounds__(256, 2) void rvq_main_v8(const float* __restrict__ x,
                                                      const float* __restrict__ cb,
                                                      const float* __restrict__ cn,
                                                      float* __restrict__ out,
                                                      float* __restrict__ loss_ws) {
  __shared__ float4 rs4[32 * 64];
  __shared__ float4 cbt[64 * 16];
  __shared__ int bestk[32];
  const int tid  = threadIdx.x;
  const int tok0 = blockIdx.x * 32;
  const int ut = tid >> 3, uc = tid & 7;
  const int ty = tid >> 4, tx = tid & 15;
  const int t0 = ty * 2;
#pragma unroll
  for (int j = 0; j < 8; ++j) {
    int c4 = uc * 8 + j;
    float4 v = *(const float4*)&x[(size_t)(tok0 + ut) * D_ + c4 * 4];
    rs4[ut * 64 + (c4 ^ ((ut >> 2) & 3))] = v;
  }
  __syncthreads();
  float lsq = 0.f;
  for (int q = 0; q < Q_; ++q) {
    const float* cbq = cb + (size_t)q * K_ * D_;
    const float* cnq = cn + q * K_;
    float v1[2], v2[2]; int k1[2], k2[2];
#pragma unroll
    for (int i = 0; i < 2; ++i) { v1[i] = v2[i] = 3.4e38f; k1[i] = k2[i] = 0x7FFFFFFF; }
    for (int nc = 0; nc < 16; ++nc) {
      float acc[2][4];
#pragma unroll
      for (int i = 0; i < 2; ++i)
#pragma unroll
        for (int j = 0; j < 4; ++j) acc[i][j] = 0.f;
      for (int dc = 0; dc < 4; ++dc) {
        __syncthreads();
#pragma unroll
        for (int i = 0; i < 4; ++i) {
          int f = i * 256 + tid;
          int row = f >> 4, c = f & 15;
          float4 v = *(const float4*)&cbq[(size_t)(nc * 64 + row) * D_ + dc * 64 + c * 4];
          cbt[row * 16 + (c ^ (row >> 2))] = v;
        }
        __syncthreads();
#pragma unroll
        for (int d4 = 0; d4 < 16; ++d4) {
          float4 a[2], b[4];
#pragma unroll
          for (int i = 0; i < 2; ++i) {
            int t = t0 + i;
            int c4 = dc * 16 + d4;
            a[i] = rs4[t * 64 + (c4 ^ ((t >> 2) & 3))];
          }
#pragma unroll
          for (int j = 0; j < 4; ++j) {
            int row = tx * 4 + j;
            b[j] = cbt[row * 16 + (d4 ^ tx)];
          }
#pragma unroll
          for (int i = 0; i < 2; ++i)
#pragma unroll
            for (int j = 0; j < 4; ++j)
              acc[i][j] += a[i].x * b[j].x + a[i].y * b[j].y +
                           a[i].z * b[j].z + a[i].w * b[j].w;
        }
      }
#pragma unroll
      for (int j = 0; j < 4; ++j) {
        int k = nc * 64 + tx * 4 + j;
        float c2 = cnq[k];
#pragma unroll
        for (int i = 0; i < 2; ++i) {
          float s = c2 - 2.f * acc[i][j];
          if (lt2(s, k, v1[i], k1[i])) { v2[i] = v1[i]; k2[i] = k1[i]; v1[i] = s; k1[i] = k; }
          else if (lt2(s, k, v2[i], k2[i])) { v2[i] = s; k2[i] = k; }
        }
      }
    }
#pragma unroll
    for (int i = 0; i < 2; ++i) {
      float a1 = v1[i]; int b1 = k1[i];
      float a2 = v2[i]; int b2 = k2[i];
#pragma unroll
      for (int off = 1; off < 16; off <<= 1) {
        float o1 = __shfl_xor(a1, off); int p1 = __shfl_xor(b1, off);
        float o2 = __shfl_xor(a2, off); int p2 = __shfl_xor(b2, off);
        if (lt2(o1, p1, a1, b1)) {
          if (lt2(a1, b1, o2, p2)) { a2 = a1; b2 = b1; } else { a2 = o2; b2 = p2; }
          a1 = o1; b1 = p1;
        } else if (lt2(o1, p1, a2, b2)) { a2 = o1; b2 = p1; }
      }
      if (tx == 0) {
        int t = t0 + i;
        int kk = b1 & (K_ - 1);
        if (a2 - a1 < MARGIN_V8) {
          int kb = b2 & (K_ - 1);
          const float* rowA = cbq + (size_t)kk * D_;
          const float* rowB = cbq + (size_t)kb * D_;
          const float* rsf = (const float*)rs4;
          const int tt = t;
          auto rd = [&](int d) -> float {
            return rsf[(tt * 64 + ((d >> 2) ^ ((tt >> 2) & 3))) * 4 + (d & 3)];
          };
          float A  = np_sum256([&](int d) { float r = rd(d); return __fmul_rn(r, r); });
          float Ea = np_einsum256([&](int d) { return __fmul_rn(rd(d), rowA[d]); });
          float Ca = np_sum256([&](int d) { float c = rowA[d]; return __fmul_rn(c, c); });
          float Eb = np_einsum256([&](int d) { return __fmul_rn(rd(d), rowB[d]); });
          float Cb = np_sum256([&](int d) { float c = rowB[d]; return __fmul_rn(c, c); });
          float da = __fadd_rn(__fsub_rn(A, __fmul_rn(2.f, Ea)), Ca);
          float db = __fadd_rn(__fsub_rn(A, __fmul_rn(2.f, Eb)), Cb);
          if (db < da || (db == da && kb < kk)) kk = kb;
        }
        bestk[t] = kk;
        out[QUANT_N + q * NTOK + tok0 + t] = (float)kk;
      }
    }
    __syncthreads();
    {
      int kk = bestk[ut] & (K_ - 1);
      const float* crow = cbq + (size_t)kk * D_;
#pragma unroll
      for (int j = 0; j < 8; ++j) {
        int c4 = uc * 8 + j;
        float4 cv = *(const float4*)&crow[c4 * 4];
        int slot = ut * 64 + (c4 ^ ((ut >> 2) & 3));
        float4 rv = rs4[slot];
        rv.x -= cv.x; rv.y -= cv.y; rv.z -= cv.z; rv.w -= cv.w;
        rs4[slot] = rv;
        lsq += rv.x * rv.x + rv.y * rv.y + rv.z * rv.z + rv.w * rv.w;
      }
    }
  }
  __syncthreads();
#pragma unroll
  for (int j = 0; j < 8; ++j) {
    int c4 = uc * 8 + j;
    float4 xv = *(const float4*)&x[(size_t)(tok0 + ut) * D_ + c4 * 4];
    float4 rv = rs4[ut * 64 + (c4 ^ ((ut >> 2) & 3))];
    float4 o;
    o.x = xv.x - rv.x; o.y = xv.y - rv.y;
    o.z = xv.z - rv.z; o.w = xv.w - rv.w;
    *(float4*)&out[(size_t)(tok0 + ut) * D_ + c4 * 4] = o;
  }
#pragma unroll
  for (int off = 32; off; off >>= 1) lsq += __shfl_xor(lsq, off);
  if ((tid & 63) == 0) atomicAdd(loss_ws, lsq);
}

// ---------------------------------------------------------------------------
__global__ void rvq_finalize(const float* __restrict__ ws,
                             float* __restrict__ out) {
  if (threadIdx.x == 0) {
    float loss = 1.25f * ws[0] * (1.0f / (float)QUANT_N);
#pragma unroll
    for (int i = 0; i < 4; ++i) out[LOSS_OFF + i] = loss;
  }
}

// ---------------------------------------------------------------------------
extern "C" void kernel_launch(void* const* d_in, const int* in_sizes, int n_in,
                              void* d_out, int out_size, void* d_ws, size_t ws_size,
                              hipStream_t stream) {
  const float* x  = (const float*)d_in[0];
  const float* cb = (const float*)d_in[1];
  if (n_in >= 2 && in_sizes[0] != QUANT_N) {
    x  = (const float*)d_in[1];
    cb = (const float*)d_in[0];
  }
  float* out = (float*)d_out;

  float* ws = (float*)d_ws;
  float* cn = ws + 64;                                  // 4096 f32
  _Float16* cbh = (_Float16*)(ws + 64 + Q_ * K_);       // 2 MB fp16 codebook
  size_t need = (size_t)(64 + Q_ * K_) * 4 + (size_t)Q_ * K_ * D_ * 2 + 256;

  rvq_zero<<<1, 1, 0, stream>>>(ws);
  if (ws_size >= need) {
    rvq_prep<<<Q_ * K_ / 4, 256, 0, stream>>>(cb, cn, cbh);
    rvq_mfma5<<<NTOK / TPB5, 512, 0, stream>>>(x, cb, cn, cbh, out, ws);
  } else {
    rvq_cnorm<<<Q_ * K_ / 4, 256, 0, stream>>>(cb, cn);
    rvq_main_v8<<<NTOK / 32, 256, 0, stream>>>(x, cb, cn, out, ws);
  }
  rvq_finalize<<<1, 64, 0, stream>>>(ws, out);
}